// Round 11
// baseline (224.580 us; speedup 1.0000x reference)
//
#include <hip/hip_runtime.h>
#include <stdint.h>

#define DIM   768
#define NHEAD 12
#define HD    64
#define BATCH 8
#define SEQ   1024
#define MROWS (BATCH * SEQ)   // 8192
#define EPSLN 1e-5f
// q pre-scaled by 0.125*log2(e); softmax shift DROPPED: |s_raw| <= 8 hard
// (LN rows have L2 norm exactly 8; Cauchy-Schwarz: |z_q.z_k|/8 <= 8), so
// p = exp2(s) <= 2981, denom <= 3e6 — fp32-safe, shift cancels in p/sum(p).
#define QK_SCALE (0.125f * 1.44269504f)

typedef __attribute__((ext_vector_type(8))) short s8v;   // 8 bf16 = MFMA A/B frag
typedef __attribute__((ext_vector_type(4))) short s4v;
typedef __attribute__((ext_vector_type(4))) float f32x4;

__device__ inline short f2bf(float f) {
    union { float f; unsigned u; } v; v.f = f;
    unsigned r = v.u + 0x7FFFu + ((v.u >> 16) & 1u);   // RNE
    return (short)(r >> 16);
}
// pack two fp32 -> two bf16 in one u32 via v_perm (round-half-up)
__device__ inline unsigned pk2bf(float lo, float hi) {
    union { float f; unsigned u; } a, b; a.f = lo; b.f = hi;
    return __builtin_amdgcn_perm(b.u + 0x8000u, a.u + 0x8000u, 0x07060302u);
}
// async global->LDS, 16 B per lane (LDS dst is wave-uniform base + lane*16)
__device__ inline void gload16(const void* g, void* l) {
    __builtin_amdgcn_global_load_lds(
        (const __attribute__((address_space(1))) void*)g,
        (__attribute__((address_space(3))) void*)l, 16, 0, 0);
}

// ---------------------------------------------------------------------------
// single fp32 -> bf16 conversion pass over x | qkv_w | proj_w (float4 units)
// ---------------------------------------------------------------------------
#define N4_X (MROWS * DIM / 4)          // 1572864
#define N4_W1 (3 * DIM * DIM / 4)       // 442368
#define N4_W2 (DIM * DIM / 4)           // 147456
__global__ __launch_bounds__(256) void cvt_all(
    const float* __restrict__ x, const float* __restrict__ w1,
    const float* __restrict__ w2, short* __restrict__ dx,
    short* __restrict__ dw1, short* __restrict__ dw2)
{
    size_t i = (size_t)blockIdx.x * 256 + threadIdx.x;
    const float* s; short* d;
    if (i < N4_X)                { s = x  + i * 4;               d = dx  + i * 4; }
    else if (i < N4_X + N4_W1)   { size_t j = i - N4_X;          s = w1 + j * 4; d = dw1 + j * 4; }
    else                         { size_t j = i - N4_X - N4_W1;  s = w2 + j * 4; d = dw2 + j * 4; }
    float4 v = *(const float4*)s;
    uint2 o; o.x = pk2bf(v.x, v.y); o.y = pk2bf(v.z, v.w);
    *(uint2*)d = o;
}

// ---------------------------------------------------------------------------
// bf16 MFMA GEMM: C = A @ W^T + bias.
// NEW this round: BK=32 double-buffer. At BK=64 the dbuf cost 64KB LDS ->
// only 2 blocks/CU (2 waves/SIMD) — too little TLP to cover L2 latency +
// barriers. BK=32 halves LDS: qkv 32KB -> 4 blocks/CU, proj 24KB -> 6.
// Same total MFMA/staging work (24 steps x 16 MFMA = 12 x 32); counted
// vmcnt kept (LPS = 4 for BM=128: 2A+2B/thread; 3 for BM=64: 1A+2B).
// One MFMA K-slice per step (K=32 = full BK). Read swizzle
// (quad ^ (l16&3)) preserves exact-coverage conflict-free LDS reads.
// Epilogue (FROZEN, r9 win): q,k,v written in MFMA-fragment order:
//   q/k: [bh][key>>5][(key>>4)&1][hf(2)][lane(64)][8]
//   v:   [bh][key>>5][et(4)][lane(64)][8]
// qkv_mode: q,k LayerNorm(64) fused (fp32, once/row); q scaled 0.125*log2e.
// plain: fp32 out + bias (BM=64 proj).
// ---------------------------------------------------------------------------
template<int BM>
__global__ __launch_bounds__(256) void gemm_mfma(
    const short* __restrict__ A, const short* __restrict__ W,
    const float* __restrict__ bias,
    short* __restrict__ oq, short* __restrict__ ok, short* __restrict__ ov,
    float* __restrict__ oplain, int Ncols, int qkv_mode,
    const float* __restrict__ gamma, const float* __restrict__ beta)
{
    constexpr int MT = BM / 32;            // m-tiles per wave
    __shared__ __align__(16) short As[2][BM * 32];
    __shared__ __align__(16) short Bs[2][128 * 32];

    const int tid  = threadIdx.x;
    const int m0   = blockIdx.y * BM;
    const int n0   = blockIdx.x * 128;
    const int w    = tid >> 6, lane = tid & 63;
    const int quad = lane >> 4, l16 = lane & 15;
    const int wm   = (w & 1) * (BM / 2), wn = (w >> 1) * 64;

    f32x4 acc[MT][4];
#pragma unroll
    for (int i = 0; i < MT; ++i)
#pragma unroll
        for (int j = 0; j < 4; ++j) acc[i][j] = (f32x4){0.f, 0.f, 0.f, 0.f};

    auto stage = [&](int buf, int k0) {
#pragma unroll
        for (int i = 0; i < BM / 64; ++i) {         // stage A slab (BM x 32)
            int f   = i * 256 + tid;
            int row = f >> 2;
            int c   = (f & 3) ^ (row & 3);
            gload16(&A[(size_t)(m0 + row) * DIM + k0 + c * 8], &As[buf][f * 8]);
        }
#pragma unroll
        for (int i = 0; i < 2; ++i) {               // stage B slab (128 x 32)
            int f   = i * 256 + tid;
            int row = f >> 2;
            int c   = (f & 3) ^ (row & 3);
            gload16(&W[(size_t)(n0 + row) * DIM + k0 + c * 8], &Bs[buf][f * 8]);
        }
    };

    constexpr int NK = DIM / 32;           // 24 K-steps
    stage(0, 0);                           // tile 0 in flight

    const int ch = (quad ^ (l16 & 3)) * 8; // read chunk (swizzle-adjusted)
    for (int t = 0; t < NK; ++t) {
        const int cur = t & 1;
        if (t + 1 < NK) {
            stage(cur ^ 1, (t + 1) * 32);  // prefetch: stays in flight past barrier
            if constexpr (BM == 128)
                asm volatile("s_waitcnt vmcnt(4)" ::: "memory");
            else
                asm volatile("s_waitcnt vmcnt(3)" ::: "memory");
        } else {
            asm volatile("s_waitcnt vmcnt(0)" ::: "memory");
        }
        __builtin_amdgcn_s_barrier();      // everyone's tile-t loads landed
        s8v af[MT], bw[4];
#pragma unroll
        for (int t2 = 0; t2 < MT; ++t2)
            af[t2] = *(const s8v*)&As[cur][(wm + t2 * 16 + l16) * 32 + ch];
#pragma unroll
        for (int t2 = 0; t2 < 4; ++t2)
            bw[t2] = *(const s8v*)&Bs[cur][(wn + t2 * 16 + l16) * 32 + ch];
#pragma unroll
        for (int mt = 0; mt < MT; ++mt)
#pragma unroll
            for (int nt = 0; nt < 4; ++nt)
                acc[mt][nt] = __builtin_amdgcn_mfma_f32_16x16x32_bf16(
                    af[mt], bw[nt], acc[mt][nt], 0, 0, 0);
        __builtin_amdgcn_s_barrier();      // reads of buf cur done before t+1 overwrites
    }

    // C layout per 16x16 tile: row m = quad*4 + i, col n = l16
    if (qkv_mode) {
        const int which = n0 / DIM;        // 0=q, 1=k, 2=v (128-tiles never cross)
        if (which == 2) {
            const int hh = (n0 + wn - 2 * DIM) >> 6;   // wave spans one head
#pragma unroll
            for (int mt = 0; mt < MT; ++mt)
#pragma unroll
                for (int nt = 0; nt < 4; ++nt) {
                    int m  = m0 + wm + mt * 16 + quad * 4;   // keys m..m+3
                    int n  = n0 + wn + nt * 16 + l16;
                    float c0 = acc[mt][nt][0] + bias[n];
                    float c1 = acc[mt][nt][1] + bias[n];
                    float c2 = acc[mt][nt][2] + bias[n];
                    float c3 = acc[mt][nt][3] + bias[n];
                    int bb = m >> 10, nn = m & 1023;
                    int bh = bb * NHEAD + hh;
                    // v frag layout: et = nt, l16s = l16, quad_s = (nn&31)>>3, j = nn&7
                    size_t addr = ((((size_t)bh * 32 + (nn >> 5)) * 4 + nt) << 9)
                                + (((nn & 31) >> 3) * 16 + l16) * 8 + (nn & 7);
                    uint2 pk; pk.x = pk2bf(c0, c1); pk.y = pk2bf(c2, c3);
                    *(uint2*)&ov[addr] = pk;
                }
        } else {
            // fused LayerNorm over the head dim (64), fp32, once per row,
            // then store in MFMA-fragment order (see layout comment above)
            const float qs = (which == 0) ? QK_SCALE : 1.0f;
            short* dst = which ? ok : oq;
            const int hh = (n0 + wn - which * DIM) >> 6;   // wave spans one head
            float ge[4], be[4];
            int suboff[4];
#pragma unroll
            for (int nt = 0; nt < 4; ++nt) {
                ge[nt] = gamma[nt * 16 + l16];
                be[nt] = beta [nt * 16 + l16] * qs;
                // e = nt*16 + l16: hf = nt>>1, equad = (nt&1)*2 + (l16>>3), j = l16&7
                suboff[nt] = (nt >> 1) * 512 + ((nt & 1) * 2 + (l16 >> 3)) * 128 + (l16 & 7);
            }
#pragma unroll
            for (int mt = 0; mt < MT; ++mt)
#pragma unroll
                for (int i = 0; i < 4; ++i) {
                    float cv[4], s = 0.f, s2 = 0.f;
#pragma unroll
                    for (int nt = 0; nt < 4; ++nt) {
                        int n = n0 + wn + nt * 16 + l16;
                        cv[nt] = acc[mt][nt][i] + bias[n];
                        s  += cv[nt];
                        s2 += cv[nt] * cv[nt];
                    }
                    s  += __shfl_xor(s, 1);  s  += __shfl_xor(s, 2);
                    s  += __shfl_xor(s, 4);  s  += __shfl_xor(s, 8);
                    s2 += __shfl_xor(s2, 1); s2 += __shfl_xor(s2, 2);
                    s2 += __shfl_xor(s2, 4); s2 += __shfl_xor(s2, 8);
                    float mu  = s * (1.f / 64.f);
                    float var = s2 * (1.f / 64.f) - mu * mu;
                    float rs  = rsqrtf(var + EPSLN) * qs;
                    int m  = m0 + wm + mt * 16 + quad * 4 + i;
                    int bb = m >> 10, nn = m & 1023;
                    int bh = bb * NHEAD + hh;
                    size_t rb = ((((size_t)bh * 32 + (nn >> 5)) * 4
                                  + ((nn >> 4) & 1) * 2) << 9) + (nn & 15) * 8;
#pragma unroll
                    for (int nt = 0; nt < 4; ++nt) {
                        float val = (cv[nt] - mu) * rs * ge[nt] + be[nt];
                        dst[rb + suboff[nt]] = f2bf(val);
                    }
                }
        }
    } else {
#pragma unroll
        for (int mt = 0; mt < MT; ++mt)
#pragma unroll
            for (int nt = 0; nt < 4; ++nt)
#pragma unroll
                for (int i = 0; i < 4; ++i) {
                    int m = m0 + wm + mt * 16 + quad * 4 + i;
                    int n = n0 + wn + nt * 16 + l16;
                    oplain[(size_t)m * Ncols + n] = acc[mt][nt][i] + bias[n];
                }
    }
}

// ---------------------------------------------------------------------------
// MFMA flash attention — EXACT r9 version (55.1us measured; r10's ones-MFMA
// denominator + 2-phase epilogue REVERTED: LDS 35.8KB dropped occupancy
// 25.5->17.8% and cost +3us). QBLK=64, fragment-ordered coalesced loads,
// XCD-chunked swizzle, VALU lacc denominator, 4-round O epilogue.
// ---------------------------------------------------------------------------
__global__ __launch_bounds__(256) void attn_mfma(
    const short* __restrict__ q, const short* __restrict__ k,
    const short* __restrict__ vt, short* __restrict__ O)
{
    // bijective XCD chunking: 1536 blocks = 8 XCDs x 192
    const int id   = blockIdx.y * gridDim.x + blockIdx.x;
    const int vid  = (id & 7) * 192 + (id >> 3);
    const int bh   = vid >> 4;
    const int q0   = (vid & 15) * 64;
    const int b    = bh / NHEAD;
    const int h    = bh % NHEAD;
    const int tid  = threadIdx.x;
    const int w    = tid >> 6;
    const int lane = tid & 63;
    const int quad = lane >> 4;
    const int l16  = lane & 15;

    __shared__ __align__(16) char smem[22528];   // P (main loop) / Obuf (epilogue)
    __shared__ float denom[4][64];

    short (*Pw)[44]   = (short(*)[44])(smem + (size_t)w * (64 * 44 * 2));
    float (*Obuf)[68] = (float(*)[68])smem;      // [64 q][64 e + pad]

    // hoist Q B-frags (pre-normalized, pre-scaled) — coalesced frag loads
    const size_t qg2 = ((size_t)bh * 64 + (q0 >> 4)) * 2;
    s8v qB[4][2];
#pragma unroll
    for (int qt = 0; qt < 4; ++qt)
#pragma unroll
        for (int hf = 0; hf < 2; ++hf)
            qB[qt][hf] = *(const s8v*)&q[((qg2 + qt * 2 + hf) << 9) + lane * 8];

    f32x4 oacc[4][4];                 // [et][qt] : O^T partials
    float lacc[4] = {0.f, 0.f, 0.f, 0.f};
#pragma unroll
    for (int a = 0; a < 4; ++a)
#pragma unroll
        for (int c = 0; c < 4; ++c) oacc[a][c] = (f32x4){0.f, 0.f, 0.f, 0.f};

    for (int jb = 0; jb < 8; ++jb) {
        const int kw = jb * 4 + w;           // this wave's 32-key window
        const size_t kb9 = (((size_t)bh * 32 + kw) * 4) << 9;

        // V^T A-frags first (consumed late at PV) — coalesced
        s8v va[4];
#pragma unroll
        for (int et = 0; et < 4; ++et)
            va[et] = *(const s8v*)&vt[kb9 + ((size_t)et << 9) + lane * 8];
        // K A-frags — coalesced
        s8v kA[2][2];
#pragma unroll
        for (int kt = 0; kt < 2; ++kt)
#pragma unroll
            for (int hf = 0; hf < 2; ++hf)
                kA[kt][hf] = *(const s8v*)&k[kb9 + ((size_t)(kt * 2 + hf) << 9) + lane * 8];

        // ---- S^T = K Q^T, exp2 (no shift), packed P[q][key] -> LDS ----
#pragma unroll
        for (int qt = 0; qt < 4; ++qt)
#pragma unroll
            for (int kt = 0; kt < 2; ++kt) {
                f32x4 c = (f32x4){0.f, 0.f, 0.f, 0.f};
                c = __builtin_amdgcn_mfma_f32_16x16x32_bf16(kA[kt][0], qB[qt][0], c, 0, 0, 0);
                c = __builtin_amdgcn_mfma_f32_16x16x32_bf16(kA[kt][1], qB[qt][1], c, 0, 0, 0);
                // C: (key = kt*16 + quad*4 + i, q = qt*16 + l16)
                float p0 = exp2f(c[0]), p1 = exp2f(c[1]);
                float p2 = exp2f(c[2]), p3 = exp2f(c[3]);
                lacc[qt] += (p0 + p1) + (p2 + p3);
                uint2 pk; pk.x = pk2bf(p0, p1); pk.y = pk2bf(p2, p3);
                *(uint2*)&Pw[qt * 16 + l16][kt * 16 + quad * 4] = pk;   // b64
            }

        // ---- P^T B-frags: B[k=key][n=q] = Pw[q][key], contiguous b128 ----
        s8v pb[4];
#pragma unroll
        for (int qt = 0; qt < 4; ++qt)
            pb[qt] = *(const s8v*)&Pw[qt * 16 + l16][quad * 8];

        // ---- O^T += V^T P^T (K = 32: one MFMA per tile) ----
        __builtin_amdgcn_s_setprio(1);
#pragma unroll
        for (int et = 0; et < 4; ++et)
#pragma unroll
            for (int qt = 0; qt < 4; ++qt)
                oacc[et][qt] = __builtin_amdgcn_mfma_f32_16x16x32_bf16(
                    va[et], pb[qt], oacc[et][qt], 0, 0, 0);
        __builtin_amdgcn_s_setprio(0);
    }

    // ---- denominator: lane holds col q = qt*16+l16; sum across quads ----
#pragma unroll
    for (int qt = 0; qt < 4; ++qt) {
        float s = lacc[qt];
        s += __shfl_xor(s, 16);
        s += __shfl_xor(s, 32);
        denom[w][qt * 16 + l16] = s;     // 4 quads write same value: benign
    }
    __syncthreads();                     // main loop done; P region now dead

    // ---- cross-wave O sum into Obuf (float4: e = et*16+quad*4 .. +3) ----
    for (int r = 0; r < 4; ++r) {
        if (w == r) {
#pragma unroll
            for (int et = 0; et < 4; ++et)
#pragma unroll
                for (int qt = 0; qt < 4; ++qt) {
                    float* dst = &Obuf[qt * 16 + l16][et * 16 + quad * 4];
                    float4 ov;
                    if (r == 0) ov = make_float4(0.f, 0.f, 0.f, 0.f);
                    else        ov = *(float4*)dst;
                    ov.x += oacc[et][qt][0]; ov.y += oacc[et][qt][1];
                    ov.z += oacc[et][qt][2]; ov.w += oacc[et][qt][3];
                    *(float4*)dst = ov;
                }
        }
        __syncthreads();
    }

    // ---- scale + store: thread t -> (q = t/4, e-span = (t%4)*16) ----
    const int qq = tid >> 2;
    const int e0 = (tid & 3) * 16;
    float linv = 1.0f / (denom[0][qq] + denom[1][qq] + denom[2][qq] + denom[3][qq]);
    float4 f0 = *(float4*)&Obuf[qq][e0];
    float4 f1 = *(float4*)&Obuf[qq][e0 + 4];
    float4 f2 = *(float4*)&Obuf[qq][e0 + 8];
    float4 f3 = *(float4*)&Obuf[qq][e0 + 12];
    short* op = &O[((size_t)b * SEQ + q0 + qq) * DIM + h * HD + e0];
    uint4 o1, o2;
    o1.x = pk2bf(f0.x * linv, f0.y * linv);
    o1.y = pk2bf(f0.z * linv, f0.w * linv);
    o1.z = pk2bf(f1.x * linv, f1.y * linv);
    o1.w = pk2bf(f1.z * linv, f1.w * linv);
    o2.x = pk2bf(f2.x * linv, f2.y * linv);
    o2.y = pk2bf(f2.z * linv, f2.w * linv);
    o2.z = pk2bf(f3.x * linv, f3.y * linv);
    o2.w = pk2bf(f3.z * linv, f3.w * linv);
    *(uint4*)&op[0] = o1;
    *(uint4*)&op[8] = o2;
}

// ---------------------------------------------------------------------------
extern "C" void kernel_launch(void* const* d_in, const int* in_sizes, int n_in,
                              void* d_out, int out_size, void* d_ws, size_t ws_size,
                              hipStream_t stream)
{
    const float* x      = (const float*)d_in[0];
    const float* qkv_w  = (const float*)d_in[1];
    const float* qkv_b  = (const float*)d_in[2];
    const float* proj_w = (const float*)d_in[3];
    const float* proj_b = (const float*)d_in[4];
    const float* gamma  = (const float*)d_in[5];
    const float* beta   = (const float*)d_in[6];
    float* out = (float*)d_out;

    const size_t PER = (size_t)BATCH * NHEAD * SEQ * HD;  // 6291456
    short* qb  = (short*)d_ws;                 // bf16 q  frag-ordered (LN'd, scaled)
    short* kb  = qb + PER;                     // bf16 k  frag-ordered (LN'd)
    short* vtb = kb + PER;                     // bf16 v  frag-ordered
    short* ob  = vtb + PER;                    // bf16 o   [B,N,768]
    short* xb  = ob + PER;                     // bf16 x   [8192,768]
    short* wqb = xb + (size_t)MROWS * DIM;     // bf16 qkv_w [2304,768]
    short* wpb = wqb + (size_t)3 * DIM * DIM;  // bf16 proj_w [768,768]

    // 0) one fused fp32 -> bf16 conversion pass
    cvt_all<<<dim3((N4_X + N4_W1 + N4_W2) / 256), 256, 0, stream>>>(
        x, qkv_w, proj_w, xb, wqb, wpb);

    // 1) qkv GEMM -> LN'd q,k + v, all in MFMA-fragment order
    gemm_mfma<128><<<dim3(2304 / 128, MROWS / 128), 256, 0, stream>>>(
        xb, wqb, qkv_b, qb, kb, vtb, nullptr, 2304, 1, gamma, beta);

    // 2) MFMA flash attention (fully coalesced loads) -> o bf16 [B,N,768]
    attn_mfma<<<dim3(SEQ / 64, BATCH * NHEAD), 256, 0, stream>>>(
        qb, kb, vtb, ob);

    // 3) out = o @ proj_w^T + proj_b (fp32 out), 64-row tiles: 768 blocks
    gemm_mfma<64><<<dim3(DIM / 128, MROWS / 64), 256, 0, stream>>>(
        ob, wpb, proj_b, nullptr, nullptr, nullptr, out, DIM, 0, nullptr, nullptr);
}

// Round 12
// 200.255 us; speedup vs baseline: 1.1215x; 1.1215x over previous
//
#include <hip/hip_runtime.h>
#include <stdint.h>

#define DIM   768
#define NHEAD 12
#define HD    64
#define BATCH 8
#define SEQ   1024
#define MROWS (BATCH * SEQ)   // 8192
#define EPSLN 1e-5f
// q pre-scaled by 0.125*log2(e); softmax shift DROPPED: |s_raw| <= 8 hard
// (LN rows have L2 norm exactly 8; Cauchy-Schwarz: |z_q.z_k|/8 <= 8), so
// p = exp2(s) <= 2981, denom <= 3e6 — fp32-safe, shift cancels in p/sum(p).
#define QK_SCALE (0.125f * 1.44269504f)

typedef __attribute__((ext_vector_type(8))) short s8v;   // 8 bf16 = MFMA A/B frag
typedef __attribute__((ext_vector_type(4))) short s4v;
typedef __attribute__((ext_vector_type(4))) float f32x4;

__device__ inline short f2bf(float f) {
    union { float f; unsigned u; } v; v.f = f;
    unsigned r = v.u + 0x7FFFu + ((v.u >> 16) & 1u);   // RNE
    return (short)(r >> 16);
}
// pack two fp32 -> two bf16 in one u32 via v_perm (round-half-up)
__device__ inline unsigned pk2bf(float lo, float hi) {
    union { float f; unsigned u; } a, b; a.f = lo; b.f = hi;
    return __builtin_amdgcn_perm(b.u + 0x8000u, a.u + 0x8000u, 0x07060302u);
}
// async global->LDS, 16 B per lane (LDS dst is wave-uniform base + lane*16)
__device__ inline void gload16(const void* g, void* l) {
    __builtin_amdgcn_global_load_lds(
        (const __attribute__((address_space(1))) void*)g,
        (__attribute__((address_space(3))) void*)l, 16, 0, 0);
}

// ---------------------------------------------------------------------------
// single fp32 -> bf16 conversion pass over x | qkv_w | proj_w (float4 units)
// ---------------------------------------------------------------------------
#define N4_X (MROWS * DIM / 4)          // 1572864
#define N4_W1 (3 * DIM * DIM / 4)       // 442368
#define N4_W2 (DIM * DIM / 4)           // 147456
__global__ __launch_bounds__(256) void cvt_all(
    const float* __restrict__ x, const float* __restrict__ w1,
    const float* __restrict__ w2, short* __restrict__ dx,
    short* __restrict__ dw1, short* __restrict__ dw2)
{
    size_t i = (size_t)blockIdx.x * 256 + threadIdx.x;
    const float* s; short* d;
    if (i < N4_X)                { s = x  + i * 4;               d = dx  + i * 4; }
    else if (i < N4_X + N4_W1)   { size_t j = i - N4_X;          s = w1 + j * 4; d = dw1 + j * 4; }
    else                         { size_t j = i - N4_X - N4_W1;  s = w2 + j * 4; d = dw2 + j * 4; }
    float4 v = *(const float4*)s;
    uint2 o; o.x = pk2bf(v.x, v.y); o.y = pk2bf(v.z, v.w);
    *(uint2*)d = o;
}

// ---------------------------------------------------------------------------
// bf16 MFMA GEMM: C = A @ W^T + bias.
// FROZEN structure (r11 lesson): BK=64 double-buffer + counted vmcnt across
// raw barriers + 8-chunk XOR read swizzle (measured 0 bank conflicts).
// BK=32 is a dead end: only 4 chunks -> unavoidable 4-way read conflicts
// (3.5M measured) since gload16 forbids padded LDS rows (m104).
// Epilogue (FROZEN, r9 win): q,k,v written in MFMA-fragment order:
//   q/k: [bh][key>>5][(key>>4)&1][hf(2)][lane(64)][8]
//   v:   [bh][key>>5][et(4)][lane(64)][8]
// qkv_mode: q,k LayerNorm(64) fused (fp32, once/row); q scaled 0.125*log2e.
// plain: fp32 out + bias. NEW this round: proj runs BM=128 (was 64) —
// 1.5x better MFMA:staging ratio, halved W re-fetch; grid 6x64=384.
// ---------------------------------------------------------------------------
template<int BM>
__global__ __launch_bounds__(256) void gemm_mfma(
    const short* __restrict__ A, const short* __restrict__ W,
    const float* __restrict__ bias,
    short* __restrict__ oq, short* __restrict__ ok, short* __restrict__ ov,
    float* __restrict__ oplain, int Ncols, int qkv_mode,
    const float* __restrict__ gamma, const float* __restrict__ beta)
{
    constexpr int MT = BM / 32;            // m-tiles per wave
    __shared__ __align__(16) short As[2][BM * 64];
    __shared__ __align__(16) short Bs[2][128 * 64];

    const int tid  = threadIdx.x;
    const int m0   = blockIdx.y * BM;
    const int n0   = blockIdx.x * 128;
    const int w    = tid >> 6, lane = tid & 63;
    const int quad = lane >> 4, l16 = lane & 15;
    const int wm   = (w & 1) * (BM / 2), wn = (w >> 1) * 64;
    const int rsw  = l16 & 7;              // read-row swizzle key

    f32x4 acc[MT][4];
#pragma unroll
    for (int i = 0; i < MT; ++i)
#pragma unroll
        for (int j = 0; j < 4; ++j) acc[i][j] = (f32x4){0.f, 0.f, 0.f, 0.f};

    auto stage = [&](int buf, int k0) {
#pragma unroll
        for (int i = 0; i < BM / 32; ++i) {         // stage A slab (BM x 64)
            int f   = i * 256 + tid;
            int row = f >> 3;
            int c   = (f & 7) ^ (row & 7);
            gload16(&A[(size_t)(m0 + row) * DIM + k0 + c * 8], &As[buf][f * 8]);
        }
#pragma unroll
        for (int i = 0; i < 4; ++i) {               // stage B slab (128 x 64)
            int f   = i * 256 + tid;
            int row = f >> 3;
            int c   = (f & 7) ^ (row & 7);
            gload16(&W[(size_t)(n0 + row) * DIM + k0 + c * 8], &Bs[buf][f * 8]);
        }
    };

    constexpr int NK = DIM / 64;           // 12 K-steps
    stage(0, 0);                           // tile 0 in flight

    for (int t = 0; t < NK; ++t) {
        const int cur = t & 1;
        if (t + 1 < NK) {
            stage(cur ^ 1, (t + 1) * 64);  // prefetch: stays in flight past barrier
            if constexpr (BM == 128)
                asm volatile("s_waitcnt vmcnt(8)" ::: "memory");
            else
                asm volatile("s_waitcnt vmcnt(6)" ::: "memory");
        } else {
            asm volatile("s_waitcnt vmcnt(0)" ::: "memory");
        }
        __builtin_amdgcn_s_barrier();      // everyone's tile-t loads landed
#pragma unroll
        for (int ks = 0; ks < 2; ++ks) {
            const int ch = ((ks * 4 + quad) ^ rsw) * 8;
            s8v af[MT], bw[4];
#pragma unroll
            for (int t2 = 0; t2 < MT; ++t2)
                af[t2] = *(const s8v*)&As[cur][(wm + t2 * 16 + l16) * 64 + ch];
#pragma unroll
            for (int t2 = 0; t2 < 4; ++t2)
                bw[t2] = *(const s8v*)&Bs[cur][(wn + t2 * 16 + l16) * 64 + ch];
#pragma unroll
            for (int mt = 0; mt < MT; ++mt)
#pragma unroll
                for (int nt = 0; nt < 4; ++nt)
                    acc[mt][nt] = __builtin_amdgcn_mfma_f32_16x16x32_bf16(
                        af[mt], bw[nt], acc[mt][nt], 0, 0, 0);
        }
        __builtin_amdgcn_s_barrier();      // reads of buf cur done before t+1 overwrites
    }

    // C layout per 16x16 tile: row m = quad*4 + i, col n = l16
    if (qkv_mode) {
        const int which = n0 / DIM;        // 0=q, 1=k, 2=v (128-tiles never cross)
        if (which == 2) {
            const int hh = (n0 + wn - 2 * DIM) >> 6;   // wave spans one head
#pragma unroll
            for (int mt = 0; mt < MT; ++mt)
#pragma unroll
                for (int nt = 0; nt < 4; ++nt) {
                    int m  = m0 + wm + mt * 16 + quad * 4;   // keys m..m+3
                    int n  = n0 + wn + nt * 16 + l16;
                    float c0 = acc[mt][nt][0] + bias[n];
                    float c1 = acc[mt][nt][1] + bias[n];
                    float c2 = acc[mt][nt][2] + bias[n];
                    float c3 = acc[mt][nt][3] + bias[n];
                    int bb = m >> 10, nn = m & 1023;
                    int bh = bb * NHEAD + hh;
                    // v frag layout: et = nt, l16s = l16, quad_s = (nn&31)>>3, j = nn&7
                    size_t addr = ((((size_t)bh * 32 + (nn >> 5)) * 4 + nt) << 9)
                                + (((nn & 31) >> 3) * 16 + l16) * 8 + (nn & 7);
                    uint2 pk; pk.x = pk2bf(c0, c1); pk.y = pk2bf(c2, c3);
                    *(uint2*)&ov[addr] = pk;
                }
        } else {
            // fused LayerNorm over the head dim (64), fp32, once per row,
            // then store in MFMA-fragment order (see layout comment above)
            const float qs = (which == 0) ? QK_SCALE : 1.0f;
            short* dst = which ? ok : oq;
            const int hh = (n0 + wn - which * DIM) >> 6;   // wave spans one head
            float ge[4], be[4];
            int suboff[4];
#pragma unroll
            for (int nt = 0; nt < 4; ++nt) {
                ge[nt] = gamma[nt * 16 + l16];
                be[nt] = beta [nt * 16 + l16] * qs;
                // e = nt*16 + l16: hf = nt>>1, equad = (nt&1)*2 + (l16>>3), j = l16&7
                suboff[nt] = (nt >> 1) * 512 + ((nt & 1) * 2 + (l16 >> 3)) * 128 + (l16 & 7);
            }
#pragma unroll
            for (int mt = 0; mt < MT; ++mt)
#pragma unroll
                for (int i = 0; i < 4; ++i) {
                    float cv[4], s = 0.f, s2 = 0.f;
#pragma unroll
                    for (int nt = 0; nt < 4; ++nt) {
                        int n = n0 + wn + nt * 16 + l16;
                        cv[nt] = acc[mt][nt][i] + bias[n];
                        s  += cv[nt];
                        s2 += cv[nt] * cv[nt];
                    }
                    s  += __shfl_xor(s, 1);  s  += __shfl_xor(s, 2);
                    s  += __shfl_xor(s, 4);  s  += __shfl_xor(s, 8);
                    s2 += __shfl_xor(s2, 1); s2 += __shfl_xor(s2, 2);
                    s2 += __shfl_xor(s2, 4); s2 += __shfl_xor(s2, 8);
                    float mu  = s * (1.f / 64.f);
                    float var = s2 * (1.f / 64.f) - mu * mu;
                    float rs  = rsqrtf(var + EPSLN) * qs;
                    int m  = m0 + wm + mt * 16 + quad * 4 + i;
                    int bb = m >> 10, nn = m & 1023;
                    int bh = bb * NHEAD + hh;
                    size_t rb = ((((size_t)bh * 32 + (nn >> 5)) * 4
                                  + ((nn >> 4) & 1) * 2) << 9) + (nn & 15) * 8;
#pragma unroll
                    for (int nt = 0; nt < 4; ++nt) {
                        float val = (cv[nt] - mu) * rs * ge[nt] + be[nt];
                        dst[rb + suboff[nt]] = f2bf(val);
                    }
                }
        }
    } else {
#pragma unroll
        for (int mt = 0; mt < MT; ++mt)
#pragma unroll
            for (int nt = 0; nt < 4; ++nt)
#pragma unroll
                for (int i = 0; i < 4; ++i) {
                    int m = m0 + wm + mt * 16 + quad * 4 + i;
                    int n = n0 + wn + nt * 16 + l16;
                    oplain[(size_t)m * Ncols + n] = acc[mt][nt][i] + bias[n];
                }
    }
}

// ---------------------------------------------------------------------------
// MFMA flash attention — EXACT r9 version (55.1us measured). QBLK=64,
// fragment-ordered coalesced loads, XCD-chunked swizzle, VALU lacc
// denominator, 4-round O epilogue.
// ---------------------------------------------------------------------------
__global__ __launch_bounds__(256) void attn_mfma(
    const short* __restrict__ q, const short* __restrict__ k,
    const short* __restrict__ vt, short* __restrict__ O)
{
    // bijective XCD chunking: 1536 blocks = 8 XCDs x 192
    const int id   = blockIdx.y * gridDim.x + blockIdx.x;
    const int vid  = (id & 7) * 192 + (id >> 3);
    const int bh   = vid >> 4;
    const int q0   = (vid & 15) * 64;
    const int b    = bh / NHEAD;
    const int h    = bh % NHEAD;
    const int tid  = threadIdx.x;
    const int w    = tid >> 6;
    const int lane = tid & 63;
    const int quad = lane >> 4;
    const int l16  = lane & 15;

    __shared__ __align__(16) char smem[22528];   // P (main loop) / Obuf (epilogue)
    __shared__ float denom[4][64];

    short (*Pw)[44]   = (short(*)[44])(smem + (size_t)w * (64 * 44 * 2));
    float (*Obuf)[68] = (float(*)[68])smem;      // [64 q][64 e + pad]

    // hoist Q B-frags (pre-normalized, pre-scaled) — coalesced frag loads
    const size_t qg2 = ((size_t)bh * 64 + (q0 >> 4)) * 2;
    s8v qB[4][2];
#pragma unroll
    for (int qt = 0; qt < 4; ++qt)
#pragma unroll
        for (int hf = 0; hf < 2; ++hf)
            qB[qt][hf] = *(const s8v*)&q[((qg2 + qt * 2 + hf) << 9) + lane * 8];

    f32x4 oacc[4][4];                 // [et][qt] : O^T partials
    float lacc[4] = {0.f, 0.f, 0.f, 0.f};
#pragma unroll
    for (int a = 0; a < 4; ++a)
#pragma unroll
        for (int c = 0; c < 4; ++c) oacc[a][c] = (f32x4){0.f, 0.f, 0.f, 0.f};

    for (int jb = 0; jb < 8; ++jb) {
        const int kw = jb * 4 + w;           // this wave's 32-key window
        const size_t kb9 = (((size_t)bh * 32 + kw) * 4) << 9;

        // V^T A-frags first (consumed late at PV) — coalesced
        s8v va[4];
#pragma unroll
        for (int et = 0; et < 4; ++et)
            va[et] = *(const s8v*)&vt[kb9 + ((size_t)et << 9) + lane * 8];
        // K A-frags — coalesced
        s8v kA[2][2];
#pragma unroll
        for (int kt = 0; kt < 2; ++kt)
#pragma unroll
            for (int hf = 0; hf < 2; ++hf)
                kA[kt][hf] = *(const s8v*)&k[kb9 + ((size_t)(kt * 2 + hf) << 9) + lane * 8];

        // ---- S^T = K Q^T, exp2 (no shift), packed P[q][key] -> LDS ----
#pragma unroll
        for (int qt = 0; qt < 4; ++qt)
#pragma unroll
            for (int kt = 0; kt < 2; ++kt) {
                f32x4 c = (f32x4){0.f, 0.f, 0.f, 0.f};
                c = __builtin_amdgcn_mfma_f32_16x16x32_bf16(kA[kt][0], qB[qt][0], c, 0, 0, 0);
                c = __builtin_amdgcn_mfma_f32_16x16x32_bf16(kA[kt][1], qB[qt][1], c, 0, 0, 0);
                // C: (key = kt*16 + quad*4 + i, q = qt*16 + l16)
                float p0 = exp2f(c[0]), p1 = exp2f(c[1]);
                float p2 = exp2f(c[2]), p3 = exp2f(c[3]);
                lacc[qt] += (p0 + p1) + (p2 + p3);
                uint2 pk; pk.x = pk2bf(p0, p1); pk.y = pk2bf(p2, p3);
                *(uint2*)&Pw[qt * 16 + l16][kt * 16 + quad * 4] = pk;   // b64
            }

        // ---- P^T B-frags: B[k=key][n=q] = Pw[q][key], contiguous b128 ----
        s8v pb[4];
#pragma unroll
        for (int qt = 0; qt < 4; ++qt)
            pb[qt] = *(const s8v*)&Pw[qt * 16 + l16][quad * 8];

        // ---- O^T += V^T P^T (K = 32: one MFMA per tile) ----
        __builtin_amdgcn_s_setprio(1);
#pragma unroll
        for (int et = 0; et < 4; ++et)
#pragma unroll
            for (int qt = 0; qt < 4; ++qt)
                oacc[et][qt] = __builtin_amdgcn_mfma_f32_16x16x32_bf16(
                    va[et], pb[qt], oacc[et][qt], 0, 0, 0);
        __builtin_amdgcn_s_setprio(0);
    }

    // ---- denominator: lane holds col q = qt*16+l16; sum across quads ----
#pragma unroll
    for (int qt = 0; qt < 4; ++qt) {
        float s = lacc[qt];
        s += __shfl_xor(s, 16);
        s += __shfl_xor(s, 32);
        denom[w][qt * 16 + l16] = s;     // 4 quads write same value: benign
    }
    __syncthreads();                     // main loop done; P region now dead

    // ---- cross-wave O sum into Obuf (float4: e = et*16+quad*4 .. +3) ----
    for (int r = 0; r < 4; ++r) {
        if (w == r) {
#pragma unroll
            for (int et = 0; et < 4; ++et)
#pragma unroll
                for (int qt = 0; qt < 4; ++qt) {
                    float* dst = &Obuf[qt * 16 + l16][et * 16 + quad * 4];
                    float4 ov;
                    if (r == 0) ov = make_float4(0.f, 0.f, 0.f, 0.f);
                    else        ov = *(float4*)dst;
                    ov.x += oacc[et][qt][0]; ov.y += oacc[et][qt][1];
                    ov.z += oacc[et][qt][2]; ov.w += oacc[et][qt][3];
                    *(float4*)dst = ov;
                }
        }
        __syncthreads();
    }

    // ---- scale + store: thread t -> (q = t/4, e-span = (t%4)*16) ----
    const int qq = tid >> 2;
    const int e0 = (tid & 3) * 16;
    float linv = 1.0f / (denom[0][qq] + denom[1][qq] + denom[2][qq] + denom[3][qq]);
    float4 f0 = *(float4*)&Obuf[qq][e0];
    float4 f1 = *(float4*)&Obuf[qq][e0 + 4];
    float4 f2 = *(float4*)&Obuf[qq][e0 + 8];
    float4 f3 = *(float4*)&Obuf[qq][e0 + 12];
    short* op = &O[((size_t)b * SEQ + q0 + qq) * DIM + h * HD + e0];
    uint4 o1, o2;
    o1.x = pk2bf(f0.x * linv, f0.y * linv);
    o1.y = pk2bf(f0.z * linv, f0.w * linv);
    o1.z = pk2bf(f1.x * linv, f1.y * linv);
    o1.w = pk2bf(f1.z * linv, f1.w * linv);
    o2.x = pk2bf(f2.x * linv, f2.y * linv);
    o2.y = pk2bf(f2.z * linv, f2.w * linv);
    o2.z = pk2bf(f3.x * linv, f3.y * linv);
    o2.w = pk2bf(f3.z * linv, f3.w * linv);
    *(uint4*)&op[0] = o1;
    *(uint4*)&op[8] = o2;
}

// ---------------------------------------------------------------------------
extern "C" void kernel_launch(void* const* d_in, const int* in_sizes, int n_in,
                              void* d_out, int out_size, void* d_ws, size_t ws_size,
                              hipStream_t stream)
{
    const float* x      = (const float*)d_in[0];
    const float* qkv_w  = (const float*)d_in[1];
    const float* qkv_b  = (const float*)d_in[2];
    const float* proj_w = (const float*)d_in[3];
    const float* proj_b = (const float*)d_in[4];
    const float* gamma  = (const float*)d_in[5];
    const float* beta   = (const float*)d_in[6];
    float* out = (float*)d_out;

    const size_t PER = (size_t)BATCH * NHEAD * SEQ * HD;  // 6291456
    short* qb  = (short*)d_ws;                 // bf16 q  frag-ordered (LN'd, scaled)
    short* kb  = qb + PER;                     // bf16 k  frag-ordered (LN'd)
    short* vtb = kb + PER;                     // bf16 v  frag-ordered
    short* ob  = vtb + PER;                    // bf16 o   [B,N,768]
    short* xb  = ob + PER;                     // bf16 x   [8192,768]
    short* wqb = xb + (size_t)MROWS * DIM;     // bf16 qkv_w [2304,768]
    short* wpb = wqb + (size_t)3 * DIM * DIM;  // bf16 proj_w [768,768]

    // 0) one fused fp32 -> bf16 conversion pass
    cvt_all<<<dim3((N4_X + N4_W1 + N4_W2) / 256), 256, 0, stream>>>(
        x, qkv_w, proj_w, xb, wqb, wpb);

    // 1) qkv GEMM -> LN'd q,k + v, all in MFMA-fragment order
    gemm_mfma<128><<<dim3(2304 / 128, MROWS / 128), 256, 0, stream>>>(
        xb, wqb, qkv_b, qb, kb, vtb, nullptr, 2304, 1, gamma, beta);

    // 2) MFMA flash attention (fully coalesced loads) -> o bf16 [B,N,768]
    attn_mfma<<<dim3(SEQ / 64, BATCH * NHEAD), 256, 0, stream>>>(
        qb, kb, vtb, ob);

    // 3) out = o @ proj_w^T + proj_b (fp32 out), BM=128: 6x64 = 384 blocks
    gemm_mfma<128><<<dim3(DIM / 128, MROWS / 128), 256, 0, stream>>>(
        ob, wpb, proj_b, nullptr, nullptr, nullptr, out, DIM, 0, nullptr, nullptr);
}